// Round 2
// baseline (221.360 us; speedup 1.0000x reference)
//
#include <hip/hip_runtime.h>
#include <stdint.h>

#define SEQ 2048

typedef __attribute__((ext_vector_type(8))) short bf16x8;
typedef __attribute__((ext_vector_type(4))) float f32x4;

typedef const __attribute__((address_space(1))) unsigned int GVT;
typedef __attribute__((address_space(3))) unsigned int LVT;

static __device__ __forceinline__ unsigned short f2bf(float f) {
  unsigned u = __builtin_bit_cast(unsigned, f);
  u += 0x7fffu + ((u >> 16) & 1u);
  return (unsigned short)(u >> 16);
}

__global__ __launch_bounds__(256) void cvt_kernel(const float* __restrict__ src,
                                                  unsigned short* __restrict__ dst, int n4) {
  int i = blockIdx.x * 256 + threadIdx.x;
  const int stride = gridDim.x * 256;
  for (; i < n4; i += stride) {
    float4 v = reinterpret_cast<const float4*>(src)[i];
    ushort4 o;
    o.x = f2bf(v.x); o.y = f2bf(v.y); o.z = f2bf(v.z); o.w = f2bf(v.w);
    reinterpret_cast<ushort4*>(dst)[i] = o;
  }
}

// ---------------- QKV GEMM: C[4096][3072] = Xbf @ Wqkv^T, scatter to q/k/vt ----------
// q: [32][2048][64] (pre-scaled by 1/8); k: [32][2048][64]; vt: [32][64][2048] (V^T)
__global__ __launch_bounds__(256, 2) void gemm_qkv_kernel(
    const unsigned short* __restrict__ A,    // [4096][1024] bf16
    const unsigned short* __restrict__ Bt,   // [3072][1024] bf16
    const float* __restrict__ bias,          // [3072]
    unsigned short* __restrict__ qb,
    unsigned short* __restrict__ kbuf,
    unsigned short* __restrict__ vtbuf) {
  __shared__ unsigned short As[128 * 32];
  __shared__ unsigned short Bs[128 * 32];
  const int tid = threadIdx.x;
  const int lane = tid & 63;
  const int wid = tid >> 6;
  const int wr = wid >> 1, wc = wid & 1;
  const int bm = blockIdx.y, bn = blockIdx.x;
  const int lr = lane & 15, hg = lane >> 4;

  f32x4 acc[4][4] = {};

  const int r0 = tid >> 2;                 // staging row for chunk tid
  const int c0 = (tid & 3) * 8;            // staging col (elements)

  for (int kt = 0; kt < 32; ++kt) {
    __syncthreads();
    const unsigned short* ga0 = A + (size_t)(bm * 128 + r0) * 1024 + kt * 32 + c0;
    const unsigned short* ga1 = A + (size_t)(bm * 128 + r0 + 64) * 1024 + kt * 32 + c0;
    const unsigned short* gb0 = Bt + (size_t)(bn * 128 + r0) * 1024 + kt * 32 + c0;
    const unsigned short* gb1 = Bt + (size_t)(bn * 128 + r0 + 64) * 1024 + kt * 32 + c0;
    __builtin_amdgcn_global_load_lds((GVT*)ga0, (LVT*)(As + tid * 8), 16, 0, 0);
    __builtin_amdgcn_global_load_lds((GVT*)ga1, (LVT*)(As + (tid + 256) * 8), 16, 0, 0);
    __builtin_amdgcn_global_load_lds((GVT*)gb0, (LVT*)(Bs + tid * 8), 16, 0, 0);
    __builtin_amdgcn_global_load_lds((GVT*)gb1, (LVT*)(Bs + (tid + 256) * 8), 16, 0, 0);
    __syncthreads();
    bf16x8 af[4], bfr[4];
#pragma unroll
    for (int i = 0; i < 4; ++i) {
      af[i] = *reinterpret_cast<const bf16x8*>(As + (wr * 64 + i * 16 + lr) * 32 + hg * 8);
      bfr[i] = *reinterpret_cast<const bf16x8*>(Bs + (wc * 64 + i * 16 + lr) * 32 + hg * 8);
    }
#pragma unroll
    for (int i = 0; i < 4; ++i)
#pragma unroll
      for (int j = 0; j < 4; ++j)
        acc[i][j] = __builtin_amdgcn_mfma_f32_16x16x32_bf16(af[i], bfr[j], acc[i][j], 0, 0, 0);
  }

#pragma unroll
  for (int j = 0; j < 4; ++j) {
    const int col = bn * 128 + wc * 64 + j * 16 + lr;
    const float bv = bias[col];
    const int which = col >> 10;            // 0=q 1=k 2=v (uniform per wave)
    const int hh = (col >> 6) & 15;
    const int dh = col & 63;
    const float scl = which == 0 ? 0.125f : 1.0f;
#pragma unroll
    for (int i = 0; i < 4; ++i) {
#pragma unroll
      for (int r = 0; r < 4; ++r) {
        const int row = bm * 128 + wr * 64 + i * 16 + hg * 4 + r;  // C row = (l>>4)*4+r
        const int b = row >> 11, n = row & 2047;
        const unsigned short val = f2bf((acc[i][j][r] + bv) * scl);
        if (which == 2) {
          vtbuf[((size_t)((b * 16 + hh) * 64 + dh)) * 2048 + n] = val;  // V^T [bh][d][key]
        } else {
          unsigned short* dst = which == 0 ? qb : kbuf;
          dst[((size_t)((b * 16 + hh) * 2048 + n)) * 64 + dh] = val;    // [bh][n][d]
        }
      }
    }
  }
}

// ---------------- Proj GEMM: out[4096][1024] fp32 = AObf @ Wproj^T + b ----------
__global__ __launch_bounds__(256, 2) void gemm_proj_kernel(
    const unsigned short* __restrict__ A,    // [4096][1024] bf16
    const unsigned short* __restrict__ Bt,   // [1024][1024] bf16
    const float* __restrict__ bias,          // [1024]
    float* __restrict__ out) {
  __shared__ unsigned short As[128 * 32];
  __shared__ unsigned short Bs[128 * 32];
  const int tid = threadIdx.x;
  const int lane = tid & 63;
  const int wid = tid >> 6;
  const int wr = wid >> 1, wc = wid & 1;
  const int bm = blockIdx.y, bn = blockIdx.x;
  const int lr = lane & 15, hg = lane >> 4;

  f32x4 acc[4][4] = {};
  const int r0 = tid >> 2;
  const int c0 = (tid & 3) * 8;

  for (int kt = 0; kt < 32; ++kt) {
    __syncthreads();
    const unsigned short* ga0 = A + (size_t)(bm * 128 + r0) * 1024 + kt * 32 + c0;
    const unsigned short* ga1 = A + (size_t)(bm * 128 + r0 + 64) * 1024 + kt * 32 + c0;
    const unsigned short* gb0 = Bt + (size_t)(bn * 128 + r0) * 1024 + kt * 32 + c0;
    const unsigned short* gb1 = Bt + (size_t)(bn * 128 + r0 + 64) * 1024 + kt * 32 + c0;
    __builtin_amdgcn_global_load_lds((GVT*)ga0, (LVT*)(As + tid * 8), 16, 0, 0);
    __builtin_amdgcn_global_load_lds((GVT*)ga1, (LVT*)(As + (tid + 256) * 8), 16, 0, 0);
    __builtin_amdgcn_global_load_lds((GVT*)gb0, (LVT*)(Bs + tid * 8), 16, 0, 0);
    __builtin_amdgcn_global_load_lds((GVT*)gb1, (LVT*)(Bs + (tid + 256) * 8), 16, 0, 0);
    __syncthreads();
    bf16x8 af[4], bfr[4];
#pragma unroll
    for (int i = 0; i < 4; ++i) {
      af[i] = *reinterpret_cast<const bf16x8*>(As + (wr * 64 + i * 16 + lr) * 32 + hg * 8);
      bfr[i] = *reinterpret_cast<const bf16x8*>(Bs + (wc * 64 + i * 16 + lr) * 32 + hg * 8);
    }
#pragma unroll
    for (int i = 0; i < 4; ++i)
#pragma unroll
      for (int j = 0; j < 4; ++j)
        acc[i][j] = __builtin_amdgcn_mfma_f32_16x16x32_bf16(af[i], bfr[j], acc[i][j], 0, 0, 0);
  }

#pragma unroll
  for (int j = 0; j < 4; ++j) {
    const int col = bn * 128 + wc * 64 + j * 16 + lr;
    const float bv = bias[col];
#pragma unroll
    for (int i = 0; i < 4; ++i)
#pragma unroll
      for (int r = 0; r < 4; ++r) {
        const int row = bm * 128 + wr * 64 + i * 16 + hg * 4 + r;
        out[(size_t)row * 1024 + col] = acc[i][j][r] + bv;
      }
  }
}

// ---------------- Flash attention, conservative: direct QK^T, P via LDS, V^T input ----
__global__ __launch_bounds__(256, 2) void attn_kernel(
    const unsigned short* __restrict__ qb,    // [32][2048][64] bf16, pre-scaled
    const unsigned short* __restrict__ kbuf,  // [32][2048][64]
    const unsigned short* __restrict__ vt,    // [32][64][2048]  (V^T per head)
    unsigned short* __restrict__ ao) {        // [4096][1024] bf16
  __shared__ unsigned short Ks[64 * 64];      // K tile [key][d], linear
  __shared__ unsigned short Vs[64 * 64];      // V^T tile [d][key], linear
  __shared__ unsigned short Ps[4][16][72];    // per-wave P [qrow][key], padded rows
  const int tid = threadIdx.x;
  const int lane = tid & 63;
  const int wid = tid >> 6;
  const int lr = lane & 15;
  const int hg = lane >> 4;                   // 0..3
  const int qt = blockIdx.x;                  // 0..31, 64 q-rows per block
  const int bh = blockIdx.y;                  // 0..31
  const size_t hbase = (size_t)bh * SEQ * 64;

  // Q A-frags in registers: wave's rows = qt*64 + wid*16 + lr; k = hg*8 (+32)
  const unsigned short* qp = qb + hbase + (size_t)(qt * 64 + wid * 16 + lr) * 64 + hg * 8;
  const bf16x8 qf0 = *reinterpret_cast<const bf16x8*>(qp);
  const bf16x8 qf1 = *reinterpret_cast<const bf16x8*>(qp + 32);

  f32x4 accO[4] = {};                         // O[row=hg*4+r][d=jd*16+lr]
  float m_run[4], l_run[4];
#pragma unroll
  for (int r = 0; r < 4; ++r) { m_run[r] = -1e30f; l_run[r] = 0.0f; }

  const int srow = tid >> 3;                  // staging row 0..31
  const int sc8 = (tid & 7) * 8;              // staging col offset (elements)

  for (int kt = 0; kt < 32; ++kt) {
    __syncthreads();                          // all waves done reading prev K/V tiles
    {
      const unsigned short* gk0 = kbuf + hbase + (size_t)(kt * 64 + srow) * 64 + sc8;
      const unsigned short* gk1 = kbuf + hbase + (size_t)(kt * 64 + srow + 32) * 64 + sc8;
      __builtin_amdgcn_global_load_lds((GVT*)gk0, (LVT*)(Ks + tid * 8), 16, 0, 0);
      __builtin_amdgcn_global_load_lds((GVT*)gk1, (LVT*)(Ks + (tid + 256) * 8), 16, 0, 0);
      const unsigned short* gv0 = vt + hbase + (size_t)srow * 2048 + kt * 64 + sc8;
      const unsigned short* gv1 = vt + hbase + (size_t)(srow + 32) * 2048 + kt * 64 + sc8;
      __builtin_amdgcn_global_load_lds((GVT*)gv0, (LVT*)(Vs + tid * 8), 16, 0, 0);
      __builtin_amdgcn_global_load_lds((GVT*)gv1, (LVT*)(Vs + (tid + 256) * 8), 16, 0, 0);
    }
    __syncthreads();                          // staged (compiler drains vmcnt at barrier)

    // S = Q K^T for this wave's 16 q-rows x 64 keys; key subtile j
    f32x4 accS[4] = {};
#pragma unroll
    for (int j = 0; j < 4; ++j) {
      const bf16x8 kf0 = *reinterpret_cast<const bf16x8*>(Ks + (j * 16 + lr) * 64 + hg * 8);
      const bf16x8 kf1 = *reinterpret_cast<const bf16x8*>(Ks + (j * 16 + lr) * 64 + 32 + hg * 8);
      accS[j] = __builtin_amdgcn_mfma_f32_16x16x32_bf16(qf0, kf0, accS[j], 0, 0, 0);
      accS[j] = __builtin_amdgcn_mfma_f32_16x16x32_bf16(qf1, kf1, accS[j], 0, 0, 0);
    }

    // online softmax; lane holds rows hg*4+r at col j*16+lr
    float mt[4];
#pragma unroll
    for (int r = 0; r < 4; ++r)
      mt[r] = fmaxf(fmaxf(accS[0][r], accS[1][r]), fmaxf(accS[2][r], accS[3][r]));
#pragma unroll
    for (int mask = 1; mask < 16; mask <<= 1)
#pragma unroll
      for (int r = 0; r < 4; ++r) mt[r] = fmaxf(mt[r], __shfl_xor(mt[r], mask));

    float corr[4];
#pragma unroll
    for (int r = 0; r < 4; ++r) {
      const float mnew = fmaxf(m_run[r], mt[r]);
      corr[r] = __expf(m_run[r] - mnew);
      m_run[r] = mnew;
    }
    float psum[4] = {0.f, 0.f, 0.f, 0.f};
#pragma unroll
    for (int j = 0; j < 4; ++j)
#pragma unroll
      for (int r = 0; r < 4; ++r) {
        const float p = __expf(accS[j][r] - m_run[r]);
        accS[j][r] = p;
        psum[r] += p;
      }
#pragma unroll
    for (int mask = 1; mask < 16; mask <<= 1)
#pragma unroll
      for (int r = 0; r < 4; ++r) psum[r] += __shfl_xor(psum[r], mask);
#pragma unroll
    for (int r = 0; r < 4; ++r) l_run[r] = l_run[r] * corr[r] + psum[r];
#pragma unroll
    for (int jd = 0; jd < 4; ++jd)
#pragma unroll
      for (int r = 0; r < 4; ++r) accO[jd][r] *= corr[r];

    // P -> per-wave LDS (acc layout -> row-major [16][72])
#pragma unroll
    for (int j = 0; j < 4; ++j)
#pragma unroll
      for (int r = 0; r < 4; ++r) Ps[wid][hg * 4 + r][j * 16 + lr] = f2bf(accS[j][r]);

    // PV: O += P(16x64) * V(64x64); A-frag from Ps, B-frag from Vs (=V^T)
    const bf16x8 pA0 = *reinterpret_cast<const bf16x8*>(&Ps[wid][lr][hg * 8]);
    const bf16x8 pA1 = *reinterpret_cast<const bf16x8*>(&Ps[wid][lr][32 + hg * 8]);
#pragma unroll
    for (int jd = 0; jd < 4; ++jd) {
      const bf16x8 v0 = *reinterpret_cast<const bf16x8*>(Vs + (jd * 16 + lr) * 64 + hg * 8);
      const bf16x8 v1 = *reinterpret_cast<const bf16x8*>(Vs + (jd * 16 + lr) * 64 + 32 + hg * 8);
      accO[jd] = __builtin_amdgcn_mfma_f32_16x16x32_bf16(pA0, v0, accO[jd], 0, 0, 0);
      accO[jd] = __builtin_amdgcn_mfma_f32_16x16x32_bf16(pA1, v1, accO[jd], 0, 0, 0);
    }
  }

  // epilogue: lane holds O rows hg*4+r, col jd*16+lr
  const int b = bh >> 4, hh = bh & 15;
  float inv[4];
#pragma unroll
  for (int r = 0; r < 4; ++r) inv[r] = 1.0f / l_run[r];
  const int qbase = qt * 64 + wid * 16;
#pragma unroll
  for (int jd = 0; jd < 4; ++jd)
#pragma unroll
    for (int r = 0; r < 4; ++r) {
      const int row = qbase + hg * 4 + r;
      ao[(size_t)(b * 2048 + row) * 1024 + hh * 64 + jd * 16 + lr] = f2bf(accO[jd][r] * inv[r]);
    }
}

extern "C" void kernel_launch(void* const* d_in, const int* in_sizes, int n_in,
                              void* d_out, int out_size, void* d_ws, size_t ws_size,
                              hipStream_t stream) {
  const float* x = (const float*)d_in[0];
  const float* w_qkv = (const float*)d_in[1];
  const float* b_qkv = (const float*)d_in[2];
  const float* w_proj = (const float*)d_in[3];
  const float* b_proj = (const float*)d_in[4];
  float* out = (float*)d_out;
  char* ws = (char*)d_ws;
  // workspace layout (40 MB): x_bf overlaid by ao_bf after it's consumed
  unsigned short* x_bf = (unsigned short*)(ws);                   // [0, 8MB)
  unsigned short* ao_bf = (unsigned short*)(ws);                  // overlay, [0, 8MB)
  unsigned short* wq_bf = (unsigned short*)(ws + (8ull << 20));   // [8, 14MB)
  unsigned short* wp_bf = (unsigned short*)(ws + (14ull << 20));  // [14, 16MB)
  unsigned short* q_bf = (unsigned short*)(ws + (16ull << 20));   // [16, 24MB)
  unsigned short* k_bf = (unsigned short*)(ws + (24ull << 20));   // [24, 32MB)
  unsigned short* vt_bf = (unsigned short*)(ws + (32ull << 20));  // [32, 40MB)  V^T

  cvt_kernel<<<1024, 256, 0, stream>>>(x, x_bf, 4096 * 1024 / 4);
  cvt_kernel<<<1024, 256, 0, stream>>>(w_qkv, wq_bf, 3072 * 1024 / 4);
  cvt_kernel<<<512, 256, 0, stream>>>(w_proj, wp_bf, 1024 * 1024 / 4);
  gemm_qkv_kernel<<<dim3(24, 32), 256, 0, stream>>>(x_bf, wq_bf, b_qkv, q_bf, k_bf, vt_bf);
  attn_kernel<<<dim3(32, 32), 256, 0, stream>>>(q_bf, k_bf, vt_bf, ao_bf);
  gemm_proj_kernel<<<dim3(8, 32), 256, 0, stream>>>(ao_bf, wp_bf, b_proj, out);
}

// Round 3
// 156.710 us; speedup vs baseline: 1.4125x; 1.4125x over previous
//
#include <hip/hip_runtime.h>
#include <stdint.h>

#define SEQ 2048

typedef __attribute__((ext_vector_type(8))) short bf16x8;
typedef __attribute__((ext_vector_type(4))) float f32x4;

typedef const __attribute__((address_space(1))) unsigned int GVT;
typedef __attribute__((address_space(3))) unsigned int LVT;

static __device__ __forceinline__ unsigned short f2bf(float f) {
  unsigned u = __builtin_bit_cast(unsigned, f);
  u += 0x7fffu + ((u >> 16) & 1u);
  return (unsigned short)(u >> 16);
}

__global__ __launch_bounds__(256) void cvt_kernel(const float* __restrict__ src,
                                                  unsigned short* __restrict__ dst, int n4) {
  int i = blockIdx.x * 256 + threadIdx.x;
  const int stride = gridDim.x * 256;
  for (; i < n4; i += stride) {
    float4 v = reinterpret_cast<const float4*>(src)[i];
    ushort4 o;
    o.x = f2bf(v.x); o.y = f2bf(v.y); o.z = f2bf(v.z); o.w = f2bf(v.w);
    reinterpret_cast<ushort4*>(dst)[i] = o;
  }
}

// ---------------- QKV GEMM: C[4096][3072] = Xbf @ Wqkv^T, scatter to q/k/vt ----------
// q: [32][2048][64] (pre-scaled by 1/8); k: [32][2048][64]; vt: [32][64][2048] (V^T)
__global__ __launch_bounds__(256, 2) void gemm_qkv_kernel(
    const unsigned short* __restrict__ A,    // [4096][1024] bf16
    const unsigned short* __restrict__ Bt,   // [3072][1024] bf16
    const float* __restrict__ bias,          // [3072]
    unsigned short* __restrict__ qb,
    unsigned short* __restrict__ kbuf,
    unsigned short* __restrict__ vtbuf) {
  __shared__ __align__(16) unsigned short As[2][128 * 32];
  __shared__ __align__(16) unsigned short Bs[2][128 * 32];
  const int tid = threadIdx.x;
  const int lane = tid & 63;
  const int wid = tid >> 6;
  const int wr = wid >> 1, wc = wid & 1;
  const int bm = blockIdx.y, bn = blockIdx.x;
  const int lr = lane & 15, hg = lane >> 4;

  f32x4 acc[4][4] = {};

  const int r0 = tid >> 2;                 // staging row
  const int c0 = (tid & 3) * 8;            // staging col (elements)

  auto STAGE = [&](int b, int kt) {
    const unsigned short* ga0 = A + (size_t)(bm * 128 + r0) * 1024 + kt * 32 + c0;
    const unsigned short* ga1 = A + (size_t)(bm * 128 + r0 + 64) * 1024 + kt * 32 + c0;
    const unsigned short* gb0 = Bt + (size_t)(bn * 128 + r0) * 1024 + kt * 32 + c0;
    const unsigned short* gb1 = Bt + (size_t)(bn * 128 + r0 + 64) * 1024 + kt * 32 + c0;
    __builtin_amdgcn_global_load_lds((GVT*)ga0, (LVT*)&As[b][tid * 8], 16, 0, 0);
    __builtin_amdgcn_global_load_lds((GVT*)ga1, (LVT*)&As[b][(tid + 256) * 8], 16, 0, 0);
    __builtin_amdgcn_global_load_lds((GVT*)gb0, (LVT*)&Bs[b][tid * 8], 16, 0, 0);
    __builtin_amdgcn_global_load_lds((GVT*)gb1, (LVT*)&Bs[b][(tid + 256) * 8], 16, 0, 0);
  };

  STAGE(0, 0);
  int cur = 0;
  for (int kt = 0; kt < 32; ++kt) {
    __syncthreads();                       // buf[cur] staged; prev reads done
    if (kt + 1 < 32) STAGE(cur ^ 1, kt + 1);
    bf16x8 af[4], bfr[4];
#pragma unroll
    for (int i = 0; i < 4; ++i) {
      af[i] = *reinterpret_cast<const bf16x8*>(&As[cur][(wr * 64 + i * 16 + lr) * 32 + hg * 8]);
      bfr[i] = *reinterpret_cast<const bf16x8*>(&Bs[cur][(wc * 64 + i * 16 + lr) * 32 + hg * 8]);
    }
#pragma unroll
    for (int i = 0; i < 4; ++i)
#pragma unroll
      for (int j = 0; j < 4; ++j)
        acc[i][j] = __builtin_amdgcn_mfma_f32_16x16x32_bf16(af[i], bfr[j], acc[i][j], 0, 0, 0);
    cur ^= 1;
  }

#pragma unroll
  for (int j = 0; j < 4; ++j) {
    const int col = bn * 128 + wc * 64 + j * 16 + lr;
    const float bv = bias[col];
    const int which = col >> 10;            // 0=q 1=k 2=v (uniform per wave)
    const int hh = (col >> 6) & 15;
    const int dh = col & 63;
    const float scl = which == 0 ? 0.125f : 1.0f;
#pragma unroll
    for (int i = 0; i < 4; ++i) {
      if (which == 2) {
        const int row0 = bm * 128 + wr * 64 + i * 16 + hg * 4;   // 4 consecutive rows
        const int b = row0 >> 11, n0 = row0 & 2047;
        ushort4 vv;
        vv.x = f2bf(acc[i][j][0] + bv);
        vv.y = f2bf(acc[i][j][1] + bv);
        vv.z = f2bf(acc[i][j][2] + bv);
        vv.w = f2bf(acc[i][j][3] + bv);
        *reinterpret_cast<ushort4*>(
            &vtbuf[((size_t)((b * 16 + hh) * 64 + dh)) * 2048 + n0]) = vv;
      } else {
        unsigned short* dst = which == 0 ? qb : kbuf;
#pragma unroll
        for (int r = 0; r < 4; ++r) {
          const int row = bm * 128 + wr * 64 + i * 16 + hg * 4 + r;
          const int b = row >> 11, n = row & 2047;
          dst[((size_t)((b * 16 + hh) * 2048 + n)) * 64 + dh] = f2bf((acc[i][j][r] + bv) * scl);
        }
      }
    }
  }
}

// ---------------- Proj GEMM: out[4096][1024] fp32 = AObf @ Wproj^T + b ----------
__global__ __launch_bounds__(256, 2) void gemm_proj_kernel(
    const unsigned short* __restrict__ A,    // [4096][1024] bf16
    const unsigned short* __restrict__ Bt,   // [1024][1024] bf16
    const float* __restrict__ bias,          // [1024]
    float* __restrict__ out) {
  __shared__ __align__(16) unsigned short As[2][128 * 32];
  __shared__ __align__(16) unsigned short Bs[2][128 * 32];
  const int tid = threadIdx.x;
  const int lane = tid & 63;
  const int wid = tid >> 6;
  const int wr = wid >> 1, wc = wid & 1;
  const int bm = blockIdx.y, bn = blockIdx.x;
  const int lr = lane & 15, hg = lane >> 4;

  f32x4 acc[4][4] = {};
  const int r0 = tid >> 2;
  const int c0 = (tid & 3) * 8;

  auto STAGE = [&](int b, int kt) {
    const unsigned short* ga0 = A + (size_t)(bm * 128 + r0) * 1024 + kt * 32 + c0;
    const unsigned short* ga1 = A + (size_t)(bm * 128 + r0 + 64) * 1024 + kt * 32 + c0;
    const unsigned short* gb0 = Bt + (size_t)(bn * 128 + r0) * 1024 + kt * 32 + c0;
    const unsigned short* gb1 = Bt + (size_t)(bn * 128 + r0 + 64) * 1024 + kt * 32 + c0;
    __builtin_amdgcn_global_load_lds((GVT*)ga0, (LVT*)&As[b][tid * 8], 16, 0, 0);
    __builtin_amdgcn_global_load_lds((GVT*)ga1, (LVT*)&As[b][(tid + 256) * 8], 16, 0, 0);
    __builtin_amdgcn_global_load_lds((GVT*)gb0, (LVT*)&Bs[b][tid * 8], 16, 0, 0);
    __builtin_amdgcn_global_load_lds((GVT*)gb1, (LVT*)&Bs[b][(tid + 256) * 8], 16, 0, 0);
  };

  STAGE(0, 0);
  int cur = 0;
  for (int kt = 0; kt < 32; ++kt) {
    __syncthreads();
    if (kt + 1 < 32) STAGE(cur ^ 1, kt + 1);
    bf16x8 af[4], bfr[4];
#pragma unroll
    for (int i = 0; i < 4; ++i) {
      af[i] = *reinterpret_cast<const bf16x8*>(&As[cur][(wr * 64 + i * 16 + lr) * 32 + hg * 8]);
      bfr[i] = *reinterpret_cast<const bf16x8*>(&Bs[cur][(wc * 64 + i * 16 + lr) * 32 + hg * 8]);
    }
#pragma unroll
    for (int i = 0; i < 4; ++i)
#pragma unroll
      for (int j = 0; j < 4; ++j)
        acc[i][j] = __builtin_amdgcn_mfma_f32_16x16x32_bf16(af[i], bfr[j], acc[i][j], 0, 0, 0);
    cur ^= 1;
  }

#pragma unroll
  for (int j = 0; j < 4; ++j) {
    const int col = bn * 128 + wc * 64 + j * 16 + lr;
    const float bv = bias[col];
#pragma unroll
    for (int i = 0; i < 4; ++i)
#pragma unroll
      for (int r = 0; r < 4; ++r) {
        const int row = bm * 128 + wr * 64 + i * 16 + hg * 4 + r;
        out[(size_t)row * 1024 + col] = acc[i][j][r] + bv;
      }
  }
}

// ---------------- Flash attention: S^T = K*Q (swapped operands), swizzled K/V LDS,
// double-buffered staging, per-lane-row softmax, P via LDS b64 writes ----------
__global__ __launch_bounds__(256, 2) void attn_kernel(
    const unsigned short* __restrict__ qb,    // [32][2048][64] bf16, pre-scaled
    const unsigned short* __restrict__ kbuf,  // [32][2048][64]
    const unsigned short* __restrict__ vt,    // [32][64][2048]  (V^T per head)
    unsigned short* __restrict__ ao) {        // [4096][1024] bf16
  __shared__ __align__(16) unsigned short Ks[2][64 * 64];   // [key][d], slot-XOR swizzled
  __shared__ __align__(16) unsigned short Vs[2][64 * 64];   // [d][key], slot-XOR swizzled
  __shared__ __align__(16) unsigned short Ps[4][32][88];    // per-wave P[q_local][key]
  const int tid = threadIdx.x;
  const int lane = tid & 63;
  const int wid = tid >> 6;
  const int lr = lane & 15;
  const int hg = lane >> 4;                   // 0..3
  const int qt = blockIdx.x;                  // 0..15, 128 q-rows per block
  const int bh = blockIdx.y;                  // 0..31
  const size_t hbase = (size_t)bh * SEQ * 64;

  // Q B-frags in registers: col=q=lr pattern; wave rows qt*128 + wid*32 + m*16 + lr
  bf16x8 qf[2][2];
#pragma unroll
  for (int m = 0; m < 2; ++m) {
    const unsigned short* qp =
        qb + hbase + (size_t)(qt * 128 + wid * 32 + m * 16 + lr) * 64 + hg * 8;
    qf[m][0] = *reinterpret_cast<const bf16x8*>(qp);
    qf[m][1] = *reinterpret_cast<const bf16x8*>(qp + 32);
  }

  f32x4 accO[2][4] = {};                      // O[q_local=hg*4+r][d=jd*16+lr] per m-subtile
  float m_run[2] = {-1e30f, -1e30f};
  float l_run[2] = {0.0f, 0.0f};

  auto STAGE = [&](int b, int kt) {
#pragma unroll
    for (int c = 0; c < 2; ++c) {
      const int t = tid + c * 256;            // chunk 0..511
      const int row = t >> 3;                 // 0..63
      const int sw = ((t & 7) ^ (row & 7)) * 8;  // inverse-swizzled source slot
      const unsigned short* gk = kbuf + hbase + (size_t)(kt * 64 + row) * 64 + sw;
      __builtin_amdgcn_global_load_lds((GVT*)gk, (LVT*)&Ks[b][t * 8], 16, 0, 0);
      const unsigned short* gv = vt + hbase + (size_t)row * 2048 + kt * 64 + sw;
      __builtin_amdgcn_global_load_lds((GVT*)gv, (LVT*)&Vs[b][t * 8], 16, 0, 0);
    }
  };

  STAGE(0, 0);
  int cur = 0;
  const int sw0 = (hg ^ (lr & 7)) * 8;        // swizzled slot for k-half 0 (row&7 == lr&7)
  const int sw1 = ((hg + 4) ^ (lr & 7)) * 8;  // swizzled slot for k-half 1

  for (int kt = 0; kt < 32; ++kt) {
    __syncthreads();                          // buf[cur] staged; prev-tile reads done
    if (kt + 1 < 32) STAGE(cur ^ 1, kt + 1);

    // S^T = K * Q : C[key][q]; lane holds key=j*16+hg*4+r, q=m*16+lr
    f32x4 accT[2][4] = {};
#pragma unroll
    for (int j = 0; j < 4; ++j) {
      const bf16x8 kf0 = *reinterpret_cast<const bf16x8*>(&Ks[cur][(j * 16 + lr) * 64 + sw0]);
      const bf16x8 kf1 = *reinterpret_cast<const bf16x8*>(&Ks[cur][(j * 16 + lr) * 64 + sw1]);
      accT[0][j] = __builtin_amdgcn_mfma_f32_16x16x32_bf16(kf0, qf[0][0], accT[0][j], 0, 0, 0);
      accT[0][j] = __builtin_amdgcn_mfma_f32_16x16x32_bf16(kf1, qf[0][1], accT[0][j], 0, 0, 0);
      accT[1][j] = __builtin_amdgcn_mfma_f32_16x16x32_bf16(kf0, qf[1][0], accT[1][j], 0, 0, 0);
      accT[1][j] = __builtin_amdgcn_mfma_f32_16x16x32_bf16(kf1, qf[1][1], accT[1][j], 0, 0, 0);
    }

    // online softmax: lane owns q=m*16+lr with 16 keys; union over hg groups = 64 keys
#pragma unroll
    for (int m = 0; m < 2; ++m) {
      float mt = accT[m][0][0];
#pragma unroll
      for (int j = 0; j < 4; ++j)
#pragma unroll
        for (int r = 0; r < 4; ++r) mt = fmaxf(mt, accT[m][j][r]);
      mt = fmaxf(mt, __shfl_xor(mt, 16));
      mt = fmaxf(mt, __shfl_xor(mt, 32));
      const float mnew = fmaxf(m_run[m], mt);
      const float crr = __expf(m_run[m] - mnew);
      m_run[m] = mnew;
      float ps = 0.0f;
#pragma unroll
      for (int j = 0; j < 4; ++j) {
        ushort4 pw;
        float p0 = __expf(accT[m][j][0] - mnew);
        float p1 = __expf(accT[m][j][1] - mnew);
        float p2 = __expf(accT[m][j][2] - mnew);
        float p3 = __expf(accT[m][j][3] - mnew);
        ps += (p0 + p1) + (p2 + p3);
        pw.x = f2bf(p0); pw.y = f2bf(p1); pw.z = f2bf(p2); pw.w = f2bf(p3);
        // keys j*16+hg*4+{0..3} contiguous -> one b64 write
        *reinterpret_cast<ushort4*>(&Ps[wid][m * 16 + lr][j * 16 + hg * 4]) = pw;
      }
      ps += __shfl_xor(ps, 16);
      ps += __shfl_xor(ps, 32);
      l_run[m] = l_run[m] * crr + ps;
      // redistribute corr from q=lr holders to O-layout rows q_local=hg*4+r
      float co[4];
#pragma unroll
      for (int r = 0; r < 4; ++r) co[r] = __shfl(crr, hg * 4 + r);
#pragma unroll
      for (int jd = 0; jd < 4; ++jd)
#pragma unroll
        for (int r = 0; r < 4; ++r) accO[m][jd][r] *= co[r];
    }

    // PV: O[q][d] += P[q][key] * V[key][d]; A=P (row=lr), B=V^T frag
    bf16x8 pA[2][2];
#pragma unroll
    for (int m = 0; m < 2; ++m) {
      pA[m][0] = *reinterpret_cast<const bf16x8*>(&Ps[wid][m * 16 + lr][hg * 8]);
      pA[m][1] = *reinterpret_cast<const bf16x8*>(&Ps[wid][m * 16 + lr][32 + hg * 8]);
    }
#pragma unroll
    for (int jd = 0; jd < 4; ++jd) {
      const bf16x8 v0 = *reinterpret_cast<const bf16x8*>(&Vs[cur][(jd * 16 + lr) * 64 + sw0]);
      const bf16x8 v1 = *reinterpret_cast<const bf16x8*>(&Vs[cur][(jd * 16 + lr) * 64 + sw1]);
      accO[0][jd] = __builtin_amdgcn_mfma_f32_16x16x32_bf16(pA[0][0], v0, accO[0][jd], 0, 0, 0);
      accO[0][jd] = __builtin_amdgcn_mfma_f32_16x16x32_bf16(pA[0][1], v1, accO[0][jd], 0, 0, 0);
      accO[1][jd] = __builtin_amdgcn_mfma_f32_16x16x32_bf16(pA[1][0], v0, accO[1][jd], 0, 0, 0);
      accO[1][jd] = __builtin_amdgcn_mfma_f32_16x16x32_bf16(pA[1][1], v1, accO[1][jd], 0, 0, 0);
    }
    cur ^= 1;
  }

  // epilogue: O rows q_local=hg*4+r; l lives at lanes lr==q_local holders -> shuffle
  const int b = bh >> 4, hh = bh & 15;
#pragma unroll
  for (int m = 0; m < 2; ++m) {
    const float invl = 1.0f / l_run[m];
    float io[4];
#pragma unroll
    for (int r = 0; r < 4; ++r) io[r] = __shfl(invl, hg * 4 + r);
    const int qbase = qt * 128 + wid * 32 + m * 16;
#pragma unroll
    for (int jd = 0; jd < 4; ++jd)
#pragma unroll
      for (int r = 0; r < 4; ++r) {
        const int row = qbase + hg * 4 + r;
        ao[(size_t)(b * 2048 + row) * 1024 + hh * 64 + jd * 16 + lr] =
            f2bf(accO[m][jd][r] * io[r]);
      }
  }
}

extern "C" void kernel_launch(void* const* d_in, const int* in_sizes, int n_in,
                              void* d_out, int out_size, void* d_ws, size_t ws_size,
                              hipStream_t stream) {
  const float* x = (const float*)d_in[0];
  const float* w_qkv = (const float*)d_in[1];
  const float* b_qkv = (const float*)d_in[2];
  const float* w_proj = (const float*)d_in[3];
  const float* b_proj = (const float*)d_in[4];
  float* out = (float*)d_out;
  char* ws = (char*)d_ws;
  unsigned short* x_bf = (unsigned short*)(ws);                   // [0, 8MB)
  unsigned short* ao_bf = (unsigned short*)(ws);                  // overlay, [0, 8MB)
  unsigned short* wq_bf = (unsigned short*)(ws + (8ull << 20));   // [8, 14MB)
  unsigned short* wp_bf = (unsigned short*)(ws + (14ull << 20));  // [14, 16MB)
  unsigned short* q_bf = (unsigned short*)(ws + (16ull << 20));   // [16, 24MB)
  unsigned short* k_bf = (unsigned short*)(ws + (24ull << 20));   // [24, 32MB)
  unsigned short* vt_bf = (unsigned short*)(ws + (32ull << 20));  // [32, 40MB)  V^T

  cvt_kernel<<<1024, 256, 0, stream>>>(x, x_bf, 4096 * 1024 / 4);
  cvt_kernel<<<1024, 256, 0, stream>>>(w_qkv, wq_bf, 3072 * 1024 / 4);
  cvt_kernel<<<512, 256, 0, stream>>>(w_proj, wp_bf, 1024 * 1024 / 4);
  gemm_qkv_kernel<<<dim3(24, 32), 256, 0, stream>>>(x_bf, wq_bf, b_qkv, q_bf, k_bf, vt_bf);
  attn_kernel<<<dim3(16, 32), 256, 0, stream>>>(q_bf, k_bf, vt_bf, ao_bf);
  gemm_proj_kernel<<<dim3(8, 32), 256, 0, stream>>>(ao_bf, wp_bf, b_proj, out);
}

// Round 4
// 136.453 us; speedup vs baseline: 1.6222x; 1.1485x over previous
//
#include <hip/hip_runtime.h>
#include <stdint.h>

#define SEQ 2048

typedef __attribute__((ext_vector_type(8))) short bf16x8;
typedef __attribute__((ext_vector_type(4))) float f32x4;

typedef const __attribute__((address_space(1))) unsigned int GVT;
typedef __attribute__((address_space(3))) unsigned int LVT;

static __device__ __forceinline__ unsigned short f2bf(float f) {
  unsigned u = __builtin_bit_cast(unsigned, f);
  u += 0x7fffu + ((u >> 16) & 1u);
  return (unsigned short)(u >> 16);
}

static __device__ __forceinline__ unsigned pk_bf16(float lo, float hi) {
  unsigned r;
  asm("v_cvt_pk_bf16_f32 %0, %1, %2" : "=v"(r) : "v"(lo), "v"(hi));
  return r;
}

__global__ __launch_bounds__(256) void cvt_kernel(const float* __restrict__ src,
                                                  unsigned short* __restrict__ dst, int n4) {
  int i = blockIdx.x * 256 + threadIdx.x;
  const int stride = gridDim.x * 256;
  for (; i < n4; i += stride) {
    float4 v = reinterpret_cast<const float4*>(src)[i];
    ushort4 o;
    o.x = f2bf(v.x); o.y = f2bf(v.y); o.z = f2bf(v.z); o.w = f2bf(v.w);
    reinterpret_cast<ushort4*>(dst)[i] = o;
  }
}

// ---------------- QKV GEMM: C[4096][3072] = Xbf @ Wqkv^T, scatter to q/k/vt ----------
// q: [32][2048][64] (pre-scaled by SCALE*log2e); k: [32][2048][64]; vt: [32][64][2048]
__global__ __launch_bounds__(256, 2) void gemm_qkv_kernel(
    const unsigned short* __restrict__ A,    // [4096][1024] bf16
    const unsigned short* __restrict__ Bt,   // [3072][1024] bf16
    const float* __restrict__ bias,          // [3072]
    unsigned short* __restrict__ qb,
    unsigned short* __restrict__ kbuf,
    unsigned short* __restrict__ vtbuf) {
  __shared__ __align__(16) unsigned short As[2][128 * 32];
  __shared__ __align__(16) unsigned short Bs[2][128 * 32];
  const int tid = threadIdx.x;
  const int lane = tid & 63;
  const int wid = tid >> 6;
  const int wr = wid >> 1, wc = wid & 1;
  const int bm = blockIdx.y, bn = blockIdx.x;
  const int lr = lane & 15, hg = lane >> 4;

  f32x4 acc[4][4] = {};

  const int r0 = tid >> 2;                 // staging row
  const int c0 = (tid & 3) * 8;            // staging col (elements)

  auto STAGE = [&](int b, int kt) {
    const unsigned short* ga0 = A + (size_t)(bm * 128 + r0) * 1024 + kt * 32 + c0;
    const unsigned short* ga1 = A + (size_t)(bm * 128 + r0 + 64) * 1024 + kt * 32 + c0;
    const unsigned short* gb0 = Bt + (size_t)(bn * 128 + r0) * 1024 + kt * 32 + c0;
    const unsigned short* gb1 = Bt + (size_t)(bn * 128 + r0 + 64) * 1024 + kt * 32 + c0;
    __builtin_amdgcn_global_load_lds((GVT*)ga0, (LVT*)&As[b][tid * 8], 16, 0, 0);
    __builtin_amdgcn_global_load_lds((GVT*)ga1, (LVT*)&As[b][(tid + 256) * 8], 16, 0, 0);
    __builtin_amdgcn_global_load_lds((GVT*)gb0, (LVT*)&Bs[b][tid * 8], 16, 0, 0);
    __builtin_amdgcn_global_load_lds((GVT*)gb1, (LVT*)&Bs[b][(tid + 256) * 8], 16, 0, 0);
  };

  STAGE(0, 0);
  int cur = 0;
  for (int kt = 0; kt < 32; ++kt) {
    __syncthreads();                       // buf[cur] staged; prev reads done
    if (kt + 1 < 32) STAGE(cur ^ 1, kt + 1);
    bf16x8 af[4], bfr[4];
#pragma unroll
    for (int i = 0; i < 4; ++i) {
      af[i] = *reinterpret_cast<const bf16x8*>(&As[cur][(wr * 64 + i * 16 + lr) * 32 + hg * 8]);
      bfr[i] = *reinterpret_cast<const bf16x8*>(&Bs[cur][(wc * 64 + i * 16 + lr) * 32 + hg * 8]);
    }
#pragma unroll
    for (int i = 0; i < 4; ++i)
#pragma unroll
      for (int j = 0; j < 4; ++j)
        acc[i][j] = __builtin_amdgcn_mfma_f32_16x16x32_bf16(af[i], bfr[j], acc[i][j], 0, 0, 0);
    cur ^= 1;
  }

#pragma unroll
  for (int j = 0; j < 4; ++j) {
    const int col = bn * 128 + wc * 64 + j * 16 + lr;
    const float bv = bias[col];
    const int which = col >> 10;            // 0=q 1=k 2=v (uniform per wave)
    const int hh = (col >> 6) & 15;
    const int dh = col & 63;
    // q pre-scaled by SCALE * log2(e) so attention can use exp2 directly
    const float scl = which == 0 ? 0.18033688011112042f : 1.0f;
#pragma unroll
    for (int i = 0; i < 4; ++i) {
      if (which == 2) {
        const int row0 = bm * 128 + wr * 64 + i * 16 + hg * 4;   // 4 consecutive rows
        const int b = row0 >> 11, n0 = row0 & 2047;
        ushort4 vv;
        vv.x = f2bf(acc[i][j][0] + bv);
        vv.y = f2bf(acc[i][j][1] + bv);
        vv.z = f2bf(acc[i][j][2] + bv);
        vv.w = f2bf(acc[i][j][3] + bv);
        *reinterpret_cast<ushort4*>(
            &vtbuf[((size_t)((b * 16 + hh) * 64 + dh)) * 2048 + n0]) = vv;
      } else {
        unsigned short* dst = which == 0 ? qb : kbuf;
#pragma unroll
        for (int r = 0; r < 4; ++r) {
          const int row = bm * 128 + wr * 64 + i * 16 + hg * 4 + r;
          const int b = row >> 11, n = row & 2047;
          dst[((size_t)((b * 16 + hh) * 2048 + n)) * 64 + dh] = f2bf((acc[i][j][r] + bv) * scl);
        }
      }
    }
  }
}

// ---------------- Proj GEMM: out[4096][1024] fp32 = AObf @ Wproj^T + b ----------
__global__ __launch_bounds__(256, 2) void gemm_proj_kernel(
    const unsigned short* __restrict__ A,    // [4096][1024] bf16
    const unsigned short* __restrict__ Bt,   // [1024][1024] bf16
    const float* __restrict__ bias,          // [1024]
    float* __restrict__ out) {
  __shared__ __align__(16) unsigned short As[2][128 * 32];
  __shared__ __align__(16) unsigned short Bs[2][128 * 32];
  const int tid = threadIdx.x;
  const int lane = tid & 63;
  const int wid = tid >> 6;
  const int wr = wid >> 1, wc = wid & 1;
  const int bm = blockIdx.y, bn = blockIdx.x;
  const int lr = lane & 15, hg = lane >> 4;

  f32x4 acc[4][4] = {};
  const int r0 = tid >> 2;
  const int c0 = (tid & 3) * 8;

  auto STAGE = [&](int b, int kt) {
    const unsigned short* ga0 = A + (size_t)(bm * 128 + r0) * 1024 + kt * 32 + c0;
    const unsigned short* ga1 = A + (size_t)(bm * 128 + r0 + 64) * 1024 + kt * 32 + c0;
    const unsigned short* gb0 = Bt + (size_t)(bn * 128 + r0) * 1024 + kt * 32 + c0;
    const unsigned short* gb1 = Bt + (size_t)(bn * 128 + r0 + 64) * 1024 + kt * 32 + c0;
    __builtin_amdgcn_global_load_lds((GVT*)ga0, (LVT*)&As[b][tid * 8], 16, 0, 0);
    __builtin_amdgcn_global_load_lds((GVT*)ga1, (LVT*)&As[b][(tid + 256) * 8], 16, 0, 0);
    __builtin_amdgcn_global_load_lds((GVT*)gb0, (LVT*)&Bs[b][tid * 8], 16, 0, 0);
    __builtin_amdgcn_global_load_lds((GVT*)gb1, (LVT*)&Bs[b][(tid + 256) * 8], 16, 0, 0);
  };

  STAGE(0, 0);
  int cur = 0;
  for (int kt = 0; kt < 32; ++kt) {
    __syncthreads();
    if (kt + 1 < 32) STAGE(cur ^ 1, kt + 1);
    bf16x8 af[4], bfr[4];
#pragma unroll
    for (int i = 0; i < 4; ++i) {
      af[i] = *reinterpret_cast<const bf16x8*>(&As[cur][(wr * 64 + i * 16 + lr) * 32 + hg * 8]);
      bfr[i] = *reinterpret_cast<const bf16x8*>(&Bs[cur][(wc * 64 + i * 16 + lr) * 32 + hg * 8]);
    }
#pragma unroll
    for (int i = 0; i < 4; ++i)
#pragma unroll
      for (int j = 0; j < 4; ++j)
        acc[i][j] = __builtin_amdgcn_mfma_f32_16x16x32_bf16(af[i], bfr[j], acc[i][j], 0, 0, 0);
    cur ^= 1;
  }

#pragma unroll
  for (int j = 0; j < 4; ++j) {
    const int col = bn * 128 + wc * 64 + j * 16 + lr;
    const float bv = bias[col];
#pragma unroll
    for (int i = 0; i < 4; ++i)
#pragma unroll
      for (int r = 0; r < 4; ++r) {
        const int row = bm * 128 + wr * 64 + i * 16 + hg * 4 + r;
        out[(size_t)row * 1024 + col] = acc[i][j][r] + bv;
      }
  }
}

// ---------------- Flash attention: S^T = K*Q, O^T = V^T*P^T (q stays on lane&15),
// exp2-domain softmax, defer-max, cvt_pk packing, XCD-swizzled grid ----------
__global__ __launch_bounds__(256, 2) void attn_kernel(
    const unsigned short* __restrict__ qb,    // [32][2048][64] bf16, pre-scaled
    const unsigned short* __restrict__ kbuf,  // [32][2048][64]
    const unsigned short* __restrict__ vt,    // [32][64][2048]  (V^T per head)
    unsigned short* __restrict__ ao) {        // [4096][1024] bf16
  __shared__ __align__(16) unsigned short Ks[2][64 * 64];   // [key][d], slot-XOR swizzled
  __shared__ __align__(16) unsigned short Vs[2][64 * 64];   // [d][key], slot-XOR swizzled
  __shared__ __align__(16) unsigned short Ps[4][32][88];    // per-wave P[q_local][key]
  const int tid = threadIdx.x;
  const int lane = tid & 63;
  const int wid = tid >> 6;
  const int lr = lane & 15;
  const int hg = lane >> 4;                   // 0..3
  // XCD-bijective swizzle (512 blocks, 512%8==0): all 16 q-tiles of a head on one XCD
  const int lin = blockIdx.y * 16 + blockIdx.x;
  const int wg = (lin & 7) * 64 + (lin >> 3);
  const int qt = wg & 15;                     // 0..15, 128 q-rows per block
  const int bh = wg >> 4;                     // 0..31
  const size_t hbase = (size_t)bh * SEQ * 64;

  // Q B-frags in registers: col=q=lr pattern; wave rows qt*128 + wid*32 + m*16 + lr
  bf16x8 qf[2][2];
#pragma unroll
  for (int m = 0; m < 2; ++m) {
    const unsigned short* qp =
        qb + hbase + (size_t)(qt * 128 + wid * 32 + m * 16 + lr) * 64 + hg * 8;
    qf[m][0] = *reinterpret_cast<const bf16x8*>(qp);
    qf[m][1] = *reinterpret_cast<const bf16x8*>(qp + 32);
  }

  f32x4 accO[2][4] = {};                      // O^T: lane q=m*16+lr, d=jd*16+hg*4+r
  float m_run[2] = {-1e30f, -1e30f};
  float l_run[2] = {0.0f, 0.0f};

  auto STAGE = [&](int b, int kt) {
#pragma unroll
    for (int c = 0; c < 2; ++c) {
      const int t = tid + c * 256;            // chunk 0..511
      const int row = t >> 3;                 // 0..63
      const int sw = ((t & 7) ^ (row & 7)) * 8;  // inverse-swizzled source slot
      const unsigned short* gk = kbuf + hbase + (size_t)(kt * 64 + row) * 64 + sw;
      __builtin_amdgcn_global_load_lds((GVT*)gk, (LVT*)&Ks[b][t * 8], 16, 0, 0);
      const unsigned short* gv = vt + hbase + (size_t)row * 2048 + kt * 64 + sw;
      __builtin_amdgcn_global_load_lds((GVT*)gv, (LVT*)&Vs[b][t * 8], 16, 0, 0);
    }
  };

  STAGE(0, 0);
  int cur = 0;
  const int sw0 = (hg ^ (lr & 7)) * 8;        // swizzled slot, k-chunk 0
  const int sw1 = ((hg + 4) ^ (lr & 7)) * 8;  // swizzled slot, k-chunk 1

  for (int kt = 0; kt < 32; ++kt) {
    __syncthreads();                          // buf[cur] staged; prev-tile reads done
    if (kt + 1 < 32) STAGE(cur ^ 1, kt + 1);

    // S^T = K * Q : lane holds key=j*16+hg*4+r, q=m*16+lr  (log2-domain scores)
    f32x4 accT[2][4] = {};
#pragma unroll
    for (int j = 0; j < 4; ++j) {
      const bf16x8 kf0 = *reinterpret_cast<const bf16x8*>(&Ks[cur][(j * 16 + lr) * 64 + sw0]);
      const bf16x8 kf1 = *reinterpret_cast<const bf16x8*>(&Ks[cur][(j * 16 + lr) * 64 + sw1]);
      accT[0][j] = __builtin_amdgcn_mfma_f32_16x16x32_bf16(kf0, qf[0][0], accT[0][j], 0, 0, 0);
      accT[0][j] = __builtin_amdgcn_mfma_f32_16x16x32_bf16(kf1, qf[0][1], accT[0][j], 0, 0, 0);
      accT[1][j] = __builtin_amdgcn_mfma_f32_16x16x32_bf16(kf0, qf[1][0], accT[1][j], 0, 0, 0);
      accT[1][j] = __builtin_amdgcn_mfma_f32_16x16x32_bf16(kf1, qf[1][1], accT[1][j], 0, 0, 0);
    }

    // online softmax in exp2 domain; lane owns q=m*16+lr
#pragma unroll
    for (int m = 0; m < 2; ++m) {
      float mt = accT[m][0][0];
#pragma unroll
      for (int j = 0; j < 4; ++j)
#pragma unroll
        for (int r = 0; r < 4; ++r) mt = fmaxf(mt, accT[m][j][r]);
      mt = fmaxf(mt, __shfl_xor(mt, 16));
      mt = fmaxf(mt, __shfl_xor(mt, 32));
      if (__any(mt > m_run[m] + 8.0f)) {      // defer-max: P bounded by 2^8
        const float mnew = fmaxf(m_run[m], mt);
        const float crr = __builtin_amdgcn_exp2f(m_run[m] - mnew);
        m_run[m] = mnew;
        l_run[m] *= crr;
#pragma unroll
        for (int jd = 0; jd < 4; ++jd)
#pragma unroll
          for (int r = 0; r < 4; ++r) accO[m][jd][r] *= crr;
      }
      float ps = 0.0f;
#pragma unroll
      for (int j = 0; j < 4; ++j) {
        const float p0 = __builtin_amdgcn_exp2f(accT[m][j][0] - m_run[m]);
        const float p1 = __builtin_amdgcn_exp2f(accT[m][j][1] - m_run[m]);
        const float p2 = __builtin_amdgcn_exp2f(accT[m][j][2] - m_run[m]);
        const float p3 = __builtin_amdgcn_exp2f(accT[m][j][3] - m_run[m]);
        ps += (p0 + p1) + (p2 + p3);
        uint2 w;
        w.x = pk_bf16(p0, p1);
        w.y = pk_bf16(p2, p3);
        *reinterpret_cast<uint2*>(&Ps[wid][m * 16 + lr][j * 16 + hg * 4]) = w;
      }
      ps += __shfl_xor(ps, 16);
      ps += __shfl_xor(ps, 32);
      l_run[m] += ps;
    }

    // PV: O^T += V^T * P^T. A=V^T frag (row=d), B=P^T frag (col=q) -- B-frag(P^T)
    // is byte-identical to A-frag(P), so Ps reads are unchanged; only operand order.
    bf16x8 pB[2][2];
#pragma unroll
    for (int m = 0; m < 2; ++m) {
      pB[m][0] = *reinterpret_cast<const bf16x8*>(&Ps[wid][m * 16 + lr][hg * 8]);
      pB[m][1] = *reinterpret_cast<const bf16x8*>(&Ps[wid][m * 16 + lr][32 + hg * 8]);
    }
#pragma unroll
    for (int jd = 0; jd < 4; ++jd) {
      const bf16x8 v0 = *reinterpret_cast<const bf16x8*>(&Vs[cur][(jd * 16 + lr) * 64 + sw0]);
      const bf16x8 v1 = *reinterpret_cast<const bf16x8*>(&Vs[cur][(jd * 16 + lr) * 64 + sw1]);
      accO[0][jd] = __builtin_amdgcn_mfma_f32_16x16x32_bf16(v0, pB[0][0], accO[0][jd], 0, 0, 0);
      accO[0][jd] = __builtin_amdgcn_mfma_f32_16x16x32_bf16(v1, pB[0][1], accO[0][jd], 0, 0, 0);
      accO[1][jd] = __builtin_amdgcn_mfma_f32_16x16x32_bf16(v0, pB[1][0], accO[1][jd], 0, 0, 0);
      accO[1][jd] = __builtin_amdgcn_mfma_f32_16x16x32_bf16(v1, pB[1][1], accO[1][jd], 0, 0, 0);
    }
    cur ^= 1;
  }

  // epilogue: lane holds q=m*16+lr, d=jd*16+hg*4+r; l_run lives on the same lanes
  const int b = bh >> 4, hh = bh & 15;
#pragma unroll
  for (int m = 0; m < 2; ++m) {
    const float invl = 1.0f / l_run[m];
    const int qrow = qt * 128 + wid * 32 + m * 16 + lr;
    unsigned short* dst = ao + (size_t)(b * 2048 + qrow) * 1024 + hh * 64;
#pragma unroll
    for (int jd = 0; jd < 4; ++jd) {
      uint2 o;
      o.x = pk_bf16(accO[m][jd][0] * invl, accO[m][jd][1] * invl);
      o.y = pk_bf16(accO[m][jd][2] * invl, accO[m][jd][3] * invl);
      *reinterpret_cast<uint2*>(dst + jd * 16 + hg * 4) = o;
    }
  }
}

extern "C" void kernel_launch(void* const* d_in, const int* in_sizes, int n_in,
                              void* d_out, int out_size, void* d_ws, size_t ws_size,
                              hipStream_t stream) {
  const float* x = (const float*)d_in[0];
  const float* w_qkv = (const float*)d_in[1];
  const float* b_qkv = (const float*)d_in[2];
  const float* w_proj = (const float*)d_in[3];
  const float* b_proj = (const float*)d_in[4];
  float* out = (float*)d_out;
  char* ws = (char*)d_ws;
  unsigned short* x_bf = (unsigned short*)(ws);                   // [0, 8MB)
  unsigned short* ao_bf = (unsigned short*)(ws);                  // overlay, [0, 8MB)
  unsigned short* wq_bf = (unsigned short*)(ws + (8ull << 20));   // [8, 14MB)
  unsigned short* wp_bf = (unsigned short*)(ws + (14ull << 20));  // [14, 16MB)
  unsigned short* q_bf = (unsigned short*)(ws + (16ull << 20));   // [16, 24MB)
  unsigned short* k_bf = (unsigned short*)(ws + (24ull << 20));   // [24, 32MB)
  unsigned short* vt_bf = (unsigned short*)(ws + (32ull << 20));  // [32, 40MB)  V^T

  cvt_kernel<<<1024, 256, 0, stream>>>(x, x_bf, 4096 * 1024 / 4);
  cvt_kernel<<<1024, 256, 0, stream>>>(w_qkv, wq_bf, 3072 * 1024 / 4);
  cvt_kernel<<<512, 256, 0, stream>>>(w_proj, wp_bf, 1024 * 1024 / 4);
  gemm_qkv_kernel<<<dim3(24, 32), 256, 0, stream>>>(x_bf, wq_bf, b_qkv, q_bf, k_bf, vt_bf);
  attn_kernel<<<dim3(16, 32), 256, 0, stream>>>(q_bf, k_bf, vt_bf, ao_bf);
  gemm_proj_kernel<<<dim3(8, 32), 256, 0, stream>>>(ao_bf, wp_bf, b_proj, out);
}